// Round 1
// baseline (296.917 us; speedup 1.0000x reference)
//
#include <hip/hip_runtime.h>
#include <stdint.h>

// SoftTree: x(65536x512) f32, gw(512x255) f32, gb(255) f32, z(256x256) f32 -> out(65536x256) f32
// g = sigmoid(x@gw+gb); leaf[l] = prod_{d=0..7} (bit(l,7-d) ? 1-g[node] : g[node]),
//   node(d,l) = (1<<d)-1 + (l >> (8-d)); out = leaf @ z^T.

typedef short bf16x8 __attribute__((ext_vector_type(8)));
typedef float f32x4  __attribute__((ext_vector_type(4)));

__device__ __forceinline__ unsigned short f2bf(float f) {
    union { float f; uint32_t u; } c; c.f = f;
    uint32_t u = c.u;
    return (unsigned short)((u + 0x7FFFu + ((u >> 16) & 1u)) >> 16);
}

// ---- prep: gw (512x255, row-major gate-fast) -> gwt bf16 [gate][k] (256x512, zero-pad gate 255)
//            z (256x256) -> zb bf16 (same layout)
__global__ void softtree_prep(const float* __restrict__ gw, const float* __restrict__ z,
                              unsigned short* __restrict__ gwt, unsigned short* __restrict__ zb) {
    int tid = blockIdx.x * 256 + threadIdx.x;      // 0 .. 131071
    int n = tid >> 9;                              // gate index 0..255
    int k = tid & 511;                             // k 0..511
    float v = (n < 255) ? gw[k * 255 + n] : 0.0f;
    gwt[tid] = f2bf(v);                            // gwt[n*512 + k]
    if (tid < 65536) zb[tid] = f2bf(z[tid]);
}

// ---- main fused kernel: 512 threads (8 waves), 64 batch rows per block, grid 1024
// wave w: wr = w&3 selects 16-row m-tile; wc = w>>2 selects 128-col n-half (both GEMMs)
__global__ __launch_bounds__(512) void softtree_main(
    const float* __restrict__ x, const float* __restrict__ gb,
    const unsigned short* __restrict__ gwt, const unsigned short* __restrict__ zb,
    float* __restrict__ out)
{
    __shared__ union {
        struct {
            unsigned short xs[64 * 72];    // x tile 64 rows x 64 k, stride 72 bf16 (pad: <=2-way conflicts)
            unsigned short gws[256 * 72];  // gw tile 256 gates x 64 k, stride 72
        } p1;
        float gs[64 * 257];                // gates f32, stride 257 (conflict-free tree reads)
    } sm;

    const int tid  = threadIdx.x;
    const int lane = tid & 63;
    const int wave = tid >> 6;
    const int q    = lane >> 4;
    const int l15  = lane & 15;
    const int wr   = wave & 3;
    const int wc   = wave >> 2;
    const int R0   = blockIdx.x * 64;

    f32x4 acc[8];
    #pragma unroll
    for (int i = 0; i < 8; ++i) acc[i] = (f32x4){0.f, 0.f, 0.f, 0.f};

    // ---------------- GEMM1: logits(64x256) = X(64x512) @ GW(512x256), BK=64 ----------------
    for (int kc = 0; kc < 8; ++kc) {
        const int k0 = kc * 64;
        __syncthreads();
        // stage X chunk: 64 rows x 64 k (1024 float4 loads; 2/thread), cvt f32->bf16
        #pragma unroll
        for (int i = 0; i < 2; ++i) {
            int e   = tid + i * 512;       // 0..1023
            int row = e >> 4;
            int kq  = e & 15;
            const float4 v = *(const float4*)(x + (size_t)(R0 + row) * 512 + k0 + kq * 4);
            uint32_t pa = f2bf(v.x) | ((uint32_t)f2bf(v.y) << 16);
            uint32_t pb = f2bf(v.z) | ((uint32_t)f2bf(v.w) << 16);
            *(uint2*)(sm.p1.xs + row * 72 + kq * 4) = make_uint2(pa, pb);
        }
        // stage GW chunk: 256 gates x 64 k bf16 (2048 x 16B; 4/thread)
        #pragma unroll
        for (int i = 0; i < 4; ++i) {
            int e  = tid + i * 512;        // 0..2047
            int n  = e >> 3;
            int kk = e & 7;
            const uint4 v = *(const uint4*)(gwt + (size_t)n * 512 + k0 + kk * 8);
            *(uint4*)(sm.p1.gws + n * 72 + kk * 8) = v;
        }
        __syncthreads();
        #pragma unroll
        for (int s = 0; s < 2; ++s) {
            bf16x8 afrag = *(const bf16x8*)(sm.p1.xs + (16 * wr + l15) * 72 + s * 32 + q * 8);
            #pragma unroll
            for (int nt = 0; nt < 8; ++nt) {
                bf16x8 bfrag = *(const bf16x8*)(sm.p1.gws + (128 * wc + nt * 16 + l15) * 72 + s * 32 + q * 8);
                acc[nt] = __builtin_amdgcn_mfma_f32_16x16x32_bf16(afrag, bfrag, acc[nt], 0, 0, 0);
            }
        }
    }
    __syncthreads();

    // ---------------- Phase 2: sigmoid -> gs (f32 in LDS) ----------------
    // C/D layout: col = lane&15, row = 4*quad + reg
    #pragma unroll
    for (int nt = 0; nt < 8; ++nt) {
        int col = 128 * wc + nt * 16 + l15;
        float gbv = (col < 255) ? gb[col] : 0.0f;
        #pragma unroll
        for (int r = 0; r < 4; ++r) {
            int rowl = 16 * wr + 4 * q + r;
            float t = acc[nt][r] + gbv;
            sm.gs[rowl * 257 + col] = 1.0f / (1.0f + __expf(-t));
        }
    }
    __syncthreads();

    // ---------------- Phase 3: leaf probs directly into GEMM2 A-fragments ----------------
    // A-frag: lane holds A[m = lane&15][k = c*32 + q*8 + j]; leaf index l = k.
    const float* gr = sm.gs + (16 * wr + l15) * 257;
    bf16x8 a2[8];
    #pragma unroll
    for (int c = 0; c < 8; ++c) {
        int G = c * 4 + q;                  // aligned 8-leaf group index (l>>3)
        float p = 1.0f;
        #pragma unroll
        for (int d = 0; d < 5; ++d) {       // shared prefix: levels 0..4
            int node = (1 << d) - 1 + (G >> (5 - d));
            int bit  = (G >> (4 - d)) & 1;
            float gv = gr[node];
            p *= bit ? (1.0f - gv) : gv;
        }
        float g5 = gr[31 + G];
        float a0 = p * g5, a1 = p - a0;
        float g6a = gr[63 + 2 * G], g6b = gr[64 + 2 * G];
        float b00 = a0 * g6a, b01 = a0 - b00;
        float b10 = a1 * g6b, b11 = a1 - b10;
        float g70 = gr[127 + 4 * G], g71 = gr[128 + 4 * G];
        float g72 = gr[129 + 4 * G], g73 = gr[130 + 4 * G];
        float lf0 = b00 * g70, lf1 = b00 - lf0;
        float lf2 = b01 * g71, lf3 = b01 - lf2;
        float lf4 = b10 * g72, lf5 = b10 - lf4;
        float lf6 = b11 * g73, lf7 = b11 - lf6;
        union { bf16x8 v; uint32_t u[4]; } pk;
        pk.u[0] = f2bf(lf0) | ((uint32_t)f2bf(lf1) << 16);
        pk.u[1] = f2bf(lf2) | ((uint32_t)f2bf(lf3) << 16);
        pk.u[2] = f2bf(lf4) | ((uint32_t)f2bf(lf5) << 16);
        pk.u[3] = f2bf(lf6) | ((uint32_t)f2bf(lf7) << 16);
        a2[c] = pk.v;
    }

    // ---------------- GEMM2: out(64x256) = leaf(64x256) @ z^T, B from L2 ----------------
    f32x4 acc2[8];
    #pragma unroll
    for (int i = 0; i < 8; ++i) acc2[i] = (f32x4){0.f, 0.f, 0.f, 0.f};
    #pragma unroll
    for (int nt = 0; nt < 8; ++nt) {
        // B[k][n]: n = lane&15 -> out col; k = c*32+q*8+j -> z[n][k] contiguous
        const unsigned short* zrow = zb + (size_t)(128 * wc + nt * 16 + l15) * 256 + q * 8;
        #pragma unroll
        for (int c = 0; c < 8; ++c) {
            bf16x8 bfrag = *(const bf16x8*)(zrow + c * 32);
            acc2[nt] = __builtin_amdgcn_mfma_f32_16x16x32_bf16(a2[c], bfrag, acc2[nt], 0, 0, 0);
        }
    }

    // ---------------- epilogue ----------------
    #pragma unroll
    for (int nt = 0; nt < 8; ++nt) {
        int col = 128 * wc + nt * 16 + l15;
        #pragma unroll
        for (int r = 0; r < 4; ++r) {
            int row = R0 + 16 * wr + 4 * q + r;
            out[(size_t)row * 256 + col] = acc2[nt][r];
        }
    }
}

extern "C" void kernel_launch(void* const* d_in, const int* in_sizes, int n_in,
                              void* d_out, int out_size, void* d_ws, size_t ws_size,
                              hipStream_t stream) {
    const float* x  = (const float*)d_in[0];
    const float* gw = (const float*)d_in[1];
    const float* gb = (const float*)d_in[2];
    const float* z  = (const float*)d_in[3];
    float* outp = (float*)d_out;

    unsigned short* gwt = (unsigned short*)d_ws;     // 256*512 bf16 = 256 KB
    unsigned short* zbf = gwt + 256 * 512;           // 256*256 bf16 = 128 KB

    softtree_prep<<<512, 256, 0, stream>>>(gw, z, gwt, zbf);
    softtree_main<<<1024, 512, 0, stream>>>(x, gb, gwt, zbf, outp);
}

// Round 2
// 281.597 us; speedup vs baseline: 1.0544x; 1.0544x over previous
//
#include <hip/hip_runtime.h>
#include <hip/hip_bf16.h>
#include <stdint.h>

// SoftTree: x(65536x512) f32, gw(512x255) f32, gb(255) f32, z(256x256) f32 -> out(65536x256) f32
// g = sigmoid(x@gw+gb); leaf = depth-8 tree products of g / (1-g); out = leaf @ z^T.

typedef short bf16x8 __attribute__((ext_vector_type(8)));
typedef float f32x4  __attribute__((ext_vector_type(4)));

__device__ __forceinline__ unsigned short f2bf(float f) {
    union { float f; uint32_t u; } c; c.f = f;
    uint32_t u = c.u;
    return (unsigned short)((u + 0x7FFFu + ((u >> 16) & 1u)) >> 16);
}

__device__ __forceinline__ uint32_t pkbf(float a, float b) {
    union { __hip_bfloat162 h; uint32_t u; } cv;
    cv.h = __float22bfloat162_rn(make_float2(a, b));   // v_cvt_pk_bf16_f32 on gfx950
    return cv.u;
}

// ---- prep: blocks 0..31 transpose gw (512x255 f32, gate-fast) -> gwt bf16 [gate][k] (256x512, row255=0)
//            blocks 32..95: z (256x256 f32) -> zb bf16
__global__ __launch_bounds__(256) void softtree_prep(
    const float* __restrict__ gw, const float* __restrict__ z,
    unsigned short* __restrict__ gwt, unsigned short* __restrict__ zb)
{
    if (blockIdx.x < 32) {
        __shared__ float tsm[64][65];
        const int k0 = (blockIdx.x >> 2) * 64;
        const int n0 = (blockIdx.x & 3) * 64;
        const int r = threadIdx.x >> 6;   // 0..3
        const int c = threadIdx.x & 63;   // 0..63
        const int n = n0 + c;
        #pragma unroll
        for (int i = 0; i < 16; ++i) {
            int kk = r + i * 4;
            tsm[kk][c] = (n < 255) ? gw[(size_t)(k0 + kk) * 255 + n] : 0.0f;
        }
        __syncthreads();
        #pragma unroll
        for (int i = 0; i < 16; ++i) {
            int nn = r + i * 4;           // local gate index
            gwt[(size_t)(n0 + nn) * 512 + k0 + c] = f2bf(tsm[c][nn]);
        }
    } else {
        int base = (blockIdx.x - 32) * 1024 + threadIdx.x * 4;
        const float4 v = *(const float4*)(z + base);
        ushort4 o;
        o.x = f2bf(v.x); o.y = f2bf(v.y); o.z = f2bf(v.z); o.w = f2bf(v.w);
        *(ushort4*)(zb + base) = o;
    }
}

// ---- main: 512 threads (8 waves), 2 row-tiles of 64 per block, grid 512.
// LDS (80 KB total):
//   [0, 65536)      gws double-buffer: buf b at b*32768; cell (gate,kgrp) at slot gate*8 + (kgrp^(gate&7)), 16B/slot
//   [65536, 81920)  xs: tile t at 65536 + t*8192; cell (row,kgrp) at slot row*8 + (kgrp^(row&7)), 16B/slot
//   gates (f32, [64][258]) alias bytes [0, 66040) after GEMM1.
__global__ __launch_bounds__(512, 4) void softtree_main(
    const float* __restrict__ x, const float* __restrict__ gb,
    const unsigned short* __restrict__ gwt, const unsigned short* __restrict__ zb,
    float* __restrict__ out)
{
    __shared__ char smraw[81920];
    float* gs = (float*)smraw;

    const int tid  = threadIdx.x;
    const int lane = tid & 63;
    const int wv   = tid >> 6;
    const int q    = lane >> 4;
    const int l15  = lane & 15;
    const int wr   = wv & 3;
    const int wc   = wv >> 2;
    const int R0   = blockIdx.x * 128;

    // ---- x reg-prefetch addressing: thread t <-> cell (row = t>>3, kgrp = (t&7)^(row&7)); LDS slot = t
    const int xrow = tid >> 3;
    const int xkg  = (tid & 7) ^ (xrow & 7);
    const float* xp0 = x + (size_t)(R0 + xrow) * 512 + xkg * 8;
    const float* xp1 = xp0 + (size_t)64 * 512;
    char* xsw0 = smraw + 65536 + tid * 16;
    char* xsw1 = xsw0 + 8192;

    // ---- gw staging (global_load_lds): per wave 4 instrs; lane's cell:
    // gate = wv*32 + j*8 + (lane>>3), kgrp = (lane&7) ^ ((lane>>3)&7); LDS slot auto = (wv*4+j)*64 + lane
    const int ggate_b = wv * 32 + (lane >> 3);
    const int gkg     = (lane & 7) ^ ((lane >> 3) & 7);
    const unsigned short* gwp[4];
    #pragma unroll
    for (int j = 0; j < 4; ++j)
        gwp[j] = gwt + (size_t)(ggate_b + j * 8) * 512 + gkg * 8;
    const uint32_t gwLds = (uint32_t)(wv * 4) * 1024;   // + j*1024 + buf*32768 (wave-uniform)

    f32x4 acc[2][8];
    #pragma unroll
    for (int t = 0; t < 2; ++t)
        #pragma unroll
        for (int i = 0; i < 8; ++i) acc[t][i] = (f32x4){0.f, 0.f, 0.f, 0.f};

    // ---- prologue: x chunk0 -> regs; gw chunk0 -> gws buf0 (async)
    float4 xa0 = *(const float4*)(xp0);
    float4 xb0 = *(const float4*)(xp0 + 4);
    float4 xa1 = *(const float4*)(xp1);
    float4 xb1 = *(const float4*)(xp1 + 4);
    #pragma unroll
    for (int j = 0; j < 4; ++j)
        __builtin_amdgcn_global_load_lds(
            (const __attribute__((address_space(1))) void*)(gwp[j]),
            (__attribute__((address_space(3))) void*)(smraw + gwLds + j * 1024),
            16, 0, 0);

    // ---- GEMM1 K-loop: BK=64, 8 iters, single-exposed-latency pipeline
    for (int kc = 0; kc < 8; ++kc) {
        const int buf = kc & 1;
        __syncthreads();   // [B1] vmcnt(0): gws[buf] + x regs ready; prev ds_reads done (WAR)

        // write x chunk kc to xs (cvt f32->bf16, 16B/thread/tile)
        union { uint4 u4; uint32_t u[4]; } w0, w1;
        w0.u[0] = pkbf(xa0.x, xa0.y); w0.u[1] = pkbf(xa0.z, xa0.w);
        w0.u[2] = pkbf(xb0.x, xb0.y); w0.u[3] = pkbf(xb0.z, xb0.w);
        w1.u[0] = pkbf(xa1.x, xa1.y); w1.u[1] = pkbf(xa1.z, xa1.w);
        w1.u[2] = pkbf(xb1.x, xb1.y); w1.u[3] = pkbf(xb1.z, xb1.w);
        *(uint4*)xsw0 = w0.u4;
        *(uint4*)xsw1 = w1.u4;

        __syncthreads();   // [B2] xs visible

        // issue NEXT chunk's loads AFTER B2 so they stay in flight through the MFMA phase
        if (kc < 7) {
            const int ko = (kc + 1) * 64;
            #pragma unroll
            for (int j = 0; j < 4; ++j)
                __builtin_amdgcn_global_load_lds(
                    (const __attribute__((address_space(1))) void*)(gwp[j] + ko),
                    (__attribute__((address_space(3))) void*)(smraw + (buf ^ 1) * 32768 + gwLds + j * 1024),
                    16, 0, 0);
            xa0 = *(const float4*)(xp0 + ko);
            xb0 = *(const float4*)(xp0 + ko + 4);
            xa1 = *(const float4*)(xp1 + ko);
            xb1 = *(const float4*)(xp1 + ko + 4);
        }

        // MFMA on chunk kc
        #pragma unroll
        for (int s = 0; s < 2; ++s) {
            const int jx = (4 * s + q) ^ (l15 & 7);
            bf16x8 a0 = *(const bf16x8*)(smraw + 65536 + ((16 * wr + l15) * 8 + jx) * 16);
            bf16x8 a1 = *(const bf16x8*)(smraw + 65536 + 8192 + ((16 * wr + l15) * 8 + jx) * 16);
            #pragma unroll
            for (int nt = 0; nt < 8; ++nt) {
                const int gate = 128 * wc + nt * 16 + l15;
                bf16x8 b = *(const bf16x8*)(smraw + buf * 32768 + (gate * 8 + jx) * 16);
                acc[0][nt] = __builtin_amdgcn_mfma_f32_16x16x32_bf16(a0, b, acc[0][nt], 0, 0, 0);
                acc[1][nt] = __builtin_amdgcn_mfma_f32_16x16x32_bf16(a1, b, acc[1][nt], 0, 0, 0);
            }
        }
    }

    // ---- per-tile: sigmoid -> gates LDS, tree -> A-frags, GEMM2, store
    float gbv[8];
    #pragma unroll
    for (int nt = 0; nt < 8; ++nt) {
        int col = 128 * wc + nt * 16 + l15;
        gbv[nt] = (col < 255) ? gb[col] : 0.0f;
    }

    for (int t = 0; t < 2; ++t) {
        __syncthreads();   // gates region free (GEMM1 / previous tile's tree reads done)

        // phase 2: C/D layout col=lane&15, row=4q+reg
        #pragma unroll
        for (int nt = 0; nt < 8; ++nt) {
            const int col = 128 * wc + nt * 16 + l15;
            #pragma unroll
            for (int r = 0; r < 4; ++r) {
                const int rowl = 16 * wr + 4 * q + r;
                float v = acc[t][nt][r] + gbv[nt];
                gs[rowl * 258 + col] = 1.0f / (1.0f + __expf(-v));
            }
        }
        __syncthreads();

        // phase 3: leaf probs -> GEMM2 A-frags. A[m=lane&15][k=c*32+q*8+j], leaf l = k, group G = l>>3 = 4c+q
        const float* gr = gs + (16 * wr + l15) * 258;
        // shared prefix over levels 0..2 (bits of c): binary tree over c
        float g0v = gr[0];
        float t1v[2] = { g0v, 1.0f - g0v };
        float t2v[4], t3v[8];
        #pragma unroll
        for (int u = 0; u < 2; ++u) {
            float gl = gr[1 + u];
            t2v[2 * u] = t1v[u] * gl; t2v[2 * u + 1] = t1v[u] - t2v[2 * u];
        }
        #pragma unroll
        for (int u = 0; u < 4; ++u) {
            float gl = gr[3 + u];
            t3v[2 * u] = t2v[u] * gl; t3v[2 * u + 1] = t2v[u] - t3v[2 * u];
        }
        bf16x8 a2[8];
        #pragma unroll
        for (int c = 0; c < 8; ++c) {
            const int G = c * 4 + q;
            float p = t3v[c];
            float g3 = gr[7 + c];                    // level 3: node 7 + (G>>2), bit (G>>1)&1 = q>>1
            p = (q & 2) ? (p - p * g3) : (p * g3);
            float g4 = gr[15 + 2 * c + (q >> 1)];    // level 4: node 15 + (G>>1), bit G&1 = q&1
            p = (q & 1) ? (p - p * g4) : (p * g4);
            float g5 = gr[31 + G];
            float a0 = p * g5, a1 = p - a0;
            float g6a = gr[63 + 2 * G], g6b = gr[64 + 2 * G];
            float b00 = a0 * g6a, b01 = a0 - b00;
            float b10 = a1 * g6b, b11 = a1 - b10;
            float g70 = gr[127 + 4 * G], g71 = gr[128 + 4 * G];
            float g72 = gr[129 + 4 * G], g73 = gr[130 + 4 * G];
            float lf0 = b00 * g70, lf1 = b00 - lf0;
            float lf2 = b01 * g71, lf3 = b01 - lf2;
            float lf4 = b10 * g72, lf5 = b10 - lf4;
            float lf6 = b11 * g73, lf7 = b11 - lf6;
            union { bf16x8 v; uint32_t u[4]; } pk;
            pk.u[0] = pkbf(lf0, lf1);
            pk.u[1] = pkbf(lf2, lf3);
            pk.u[2] = pkbf(lf4, lf5);
            pk.u[3] = pkbf(lf6, lf7);
            a2[c] = pk.v;
        }

        // GEMM2: out_tile = leaf @ z^T, B-frags straight from L2-resident zb
        f32x4 acc2[8];
        #pragma unroll
        for (int i = 0; i < 8; ++i) acc2[i] = (f32x4){0.f, 0.f, 0.f, 0.f};
        #pragma unroll
        for (int nt = 0; nt < 8; ++nt) {
            const unsigned short* zrow = zb + (size_t)(128 * wc + nt * 16 + l15) * 256 + q * 8;
            #pragma unroll
            for (int c = 0; c < 8; ++c) {
                bf16x8 b = *(const bf16x8*)(zrow + c * 32);
                acc2[nt] = __builtin_amdgcn_mfma_f32_16x16x32_bf16(a2[c], b, acc2[nt], 0, 0, 0);
            }
        }

        // epilogue
        #pragma unroll
        for (int nt = 0; nt < 8; ++nt) {
            const int col = 128 * wc + nt * 16 + l15;
            #pragma unroll
            for (int r = 0; r < 4; ++r) {
                const int row = R0 + t * 64 + 16 * wr + 4 * q + r;
                out[(size_t)row * 256 + col] = acc2[nt][r];
            }
        }
    }
}

extern "C" void kernel_launch(void* const* d_in, const int* in_sizes, int n_in,
                              void* d_out, int out_size, void* d_ws, size_t ws_size,
                              hipStream_t stream) {
    const float* x  = (const float*)d_in[0];
    const float* gw = (const float*)d_in[1];
    const float* gb = (const float*)d_in[2];
    const float* z  = (const float*)d_in[3];
    float* outp = (float*)d_out;

    unsigned short* gwt = (unsigned short*)d_ws;     // 256*512 bf16 = 256 KB
    unsigned short* zbf = gwt + 256 * 512;           // 256*256 bf16 = 128 KB

    softtree_prep<<<96, 256, 0, stream>>>(gw, z, gwt, zbf);
    softtree_main<<<512, 512, 0, stream>>>(x, gb, gwt, zbf, outp);
}